// Round 6
// baseline (279.622 us; speedup 1.0000x reference)
//
#include <hip/hip_runtime.h>

// x[B,S,DM] -> QKV proj (one merged GEMM) -> causal flash attn -> out proj.
// B=2 S=4096 H=12 D=64 DM=768. fp32 in/out; internal bf16 MFMA.

#define B_ 2
#define S_ 4096
#define H_ 12
#define D_ 64
#define DM_ 768
#define MTOT (B_*S_)               // 8192
#define NE (B_*H_*S_*D_)           // 6291456 == MTOT*DM_
#define WQKV_ELEMS (3*H_*D_*DM_)   // 1769472
#define CSCALE 0.18033688011f      // 0.125 * log2(e): softmax in exp2 domain

using bf8 = __attribute__((ext_vector_type(8))) short;
using f4  = __attribute__((ext_vector_type(4))) float;
typedef unsigned int u32;
typedef unsigned long long u64;

__device__ __forceinline__ short f2bf(float f) {
    union { float f; unsigned u; } x{f};
    unsigned r = x.u + 0x7FFFu + ((x.u >> 16) & 1u);   // RNE
    return (short)(r >> 16);
}

// packed f32x2 -> bf16x2 (RNE), one instruction
__device__ __forceinline__ u32 cvtpk(float lo, float hi) {
    u32 r;
    asm("v_cvt_pk_bf16_f32 %0, %1, %2" : "=v"(r) : "v"(lo), "v"(hi));
    return r;
}

// async global->LDS, 16B per lane. LDS dest: wave-uniform base + lane*16.
__device__ __forceinline__ void gll16(const void* g, const void* l) {
    __builtin_amdgcn_global_load_lds(
        (const __attribute__((address_space(1))) u32*)g,
        (__attribute__((address_space(3))) u32*)l, 16, 0, 0);
}

// ---------------- Kernel 0: fused prep ----------------
// blocks [0,3072): x f32->bf16. [3072,3504): Wq/Wk/Wv transpose-convert
// (144 blocks each, per-head 768x64 -> 64x768). [3504,3648): Wo (768x768 -> T).
__global__ __launch_bounds__(256) void prep_kernel(
    const float* __restrict__ x, short* __restrict__ xb,
    const float* __restrict__ Wq, const float* __restrict__ Wk,
    const float* __restrict__ Wv, const float* __restrict__ Wo,
    short* __restrict__ wcat, short* __restrict__ wo_t)
{
    __shared__ short Ts[64][72];
    const int t = threadIdx.x;
    int id = blockIdx.x;
    if (id < 3072) {
        const long i = ((long)id * 256 + t) * 8;
        float4 v0 = *(const float4*)(x + i);
        float4 v1 = *(const float4*)(x + i + 4);
        bf8 pk;
        pk[0]=f2bf(v0.x); pk[1]=f2bf(v0.y); pk[2]=f2bf(v0.z); pk[3]=f2bf(v0.w);
        pk[4]=f2bf(v1.x); pk[5]=f2bf(v1.y); pk[6]=f2bf(v1.z); pk[7]=f2bf(v1.w);
        *(bf8*)(xb + i) = pk;
        return;
    }
    id -= 3072;
    const float* src; short* dst; int C, bx, by, bz;
    if (id < 432) {
        const int m = id / 144;
        src = (m == 0) ? Wq : (m == 1) ? Wk : Wv;
        dst = wcat + (long)m * H_ * D_ * DM_;
        C = D_;
        id -= m * 144;
        bx = id % 12; by = 0; bz = id / 12;
    } else {
        id -= 432;
        src = Wo; dst = wo_t; C = DM_;
        bx = id % 12; by = id / 12; bz = 0;
    }
    const long moff = (long)bz * DM_ * C;
    const int r0 = bx * 64, c0 = by * 64;
    {
        const int r = t >> 2, cq = (t & 3) * 16;
        const float* s = src + moff + (long)(r0 + r) * C + c0 + cq;
        float4 a = *(const float4*)s;
        float4 b = *(const float4*)(s + 4);
        float4 c = *(const float4*)(s + 8);
        float4 d = *(const float4*)(s + 12);
        float vv[16] = {a.x,a.y,a.z,a.w,b.x,b.y,b.z,b.w,c.x,c.y,c.z,c.w,d.x,d.y,d.z,d.w};
#pragma unroll
        for (int i = 0; i < 16; i++) Ts[cq + i][r] = f2bf(vv[i]);
    }
    __syncthreads();
    {
        const int c = t >> 2, rq = (t & 3) * 16;
        bf8 o0 = *(const bf8*)&Ts[c][rq];
        bf8 o1 = *(const bf8*)&Ts[c][rq + 8];
        short* d = dst + moff + (long)(c0 + c) * DM_ + r0 + rq;
        *(bf8*)d = o0;
        *(bf8*)(d + 8) = o1;
    }
}

// ---------------- Kernel 1: merged QKV GEMM ----------------
// C[8192 x 2304] = xb[8192x768] * wcat[2304x768]^T. 128x128 tile, BK=64,
// double-buffered gload_lds (XOR-swizzled source), precomputed LDS bases.
__global__ __launch_bounds__(256) void qkv_gemm(
    const short* __restrict__ xb, const short* __restrict__ wcat,
    const float* __restrict__ bq, const float* __restrict__ bk, const float* __restrict__ bv,
    short* __restrict__ qws, short* __restrict__ kws, short* __restrict__ vtw)
{
    __shared__ __align__(16) short As[2][8192];   // [128][64] bf16, swizzled
    __shared__ __align__(16) short Bs[2][8192];

    const int o = (blockIdx.x & 7) * 144 + (blockIdx.x >> 3);  // XCD swizzle (1152=8*144)
    const int by = o % 18, bx = o / 18;
    const int m0 = bx * 128, n0 = by * 128;
    const int e  = by / 6;               // 0:Q 1:K 2:V, uniform per block
    const int t = threadIdx.x, w = t >> 6, l = t & 63, lr = l & 15, lg = (l >> 4) & 3;
    const int wr = w >> 1, wc = w & 1;
    const int lrow = l >> 3, lseg = l & 7;
    const int colo = (lseg ^ lrow) * 8;
    const int sw = (lr & 7) << 3;
    const int ab[2] = { (wr*64 + lr)*64 + ((lg*8) ^ sw), (wr*64 + lr)*64 + ((32 + lg*8) ^ sw) };
    const int bb[2] = { (wc*64 + lr)*64 + ((lg*8) ^ sw), (wc*64 + lr)*64 + ((32 + lg*8) ^ sw) };

    const short* xp = xb   + (long)(m0 + w*32 + lrow) * DM_ + colo;
    const short* wp = wcat + (long)(n0 + w*32 + lrow) * DM_ + colo;

    auto stage = [&](int bufi) {
#pragma unroll
        for (int qq = 0; qq < 4; qq++) {
            gll16(xp + qq*8*DM_, &As[bufi][(w*256 + qq*64) * 8]);
            gll16(wp + qq*8*DM_, &Bs[bufi][(w*256 + qq*64) * 8]);
        }
        xp += 64; wp += 64;
    };

    f4 acc[4][4];
#pragma unroll
    for (int mi = 0; mi < 4; mi++)
#pragma unroll
        for (int ni = 0; ni < 4; ni++) acc[mi][ni] = (f4){0.f,0.f,0.f,0.f};

    stage(0);
    __syncthreads();

    for (int k0 = 0, it = 0; k0 < DM_; k0 += 64, it++) {
        const int cur = it & 1;
        if (k0 + 64 < DM_) stage(cur ^ 1);
        const short* Ac = As[cur];
        const short* Bc = Bs[cur];
#pragma unroll
        for (int kh = 0; kh < 2; kh++) {
            bf8 af[4], bfr[4];
#pragma unroll
            for (int mi = 0; mi < 4; mi++) af[mi]  = *(const bf8*)(Ac + mi*1024 + ab[kh]);
#pragma unroll
            for (int ni = 0; ni < 4; ni++) bfr[ni] = *(const bf8*)(Bc + ni*1024 + bb[kh]);
            if (e < 2) {
#pragma unroll
                for (int mi = 0; mi < 4; mi++)
#pragma unroll
                    for (int ni = 0; ni < 4; ni++)
                        acc[mi][ni] = __builtin_amdgcn_mfma_f32_16x16x32_bf16(af[mi], bfr[ni], acc[mi][ni], 0, 0, 0);
            } else {
#pragma unroll
                for (int mi = 0; mi < 4; mi++)
#pragma unroll
                    for (int ni = 0; ni < 4; ni++)  // D = W x^T (V^T tile)
                        acc[mi][ni] = __builtin_amdgcn_mfma_f32_16x16x32_bf16(bfr[ni], af[mi], acc[mi][ni], 0, 0, 0);
            }
        }
        __syncthreads();
    }

    if (e < 2) {
        const float scale = (e == 0) ? CSCALE : 1.f;
        const float* barr = (e == 0) ? bq : bk;
        short* dst = (e == 0) ? qws : kws;
#pragma unroll
        for (int ni = 0; ni < 4; ni++) {
            const int rem = (n0 - e*DM_) + wc*64 + ni*16 + lr;   // h*64+z
            const int hh = rem >> 6, z = rem & 63;
            const float bias = barr[rem];
#pragma unroll
            for (int mi = 0; mi < 4; mi++)
#pragma unroll
                for (int r = 0; r < 4; r++) {
                    const int m = m0 + wr*64 + mi*16 + lg*4 + r;
                    const int bb2 = m >> 12, s = m & (S_ - 1);
                    dst[((long)(bb2*H_ + hh) * S_ + s) * D_ + z] = f2bf((acc[mi][ni][r] + bias) * scale);
                }
        }
    } else {
        // D rows = z (n-dim), cols = m: coalesced V^T stores
#pragma unroll
        for (int ni = 0; ni < 4; ni++)
#pragma unroll
            for (int r = 0; r < 4; r++) {
                const int nabs = (n0 - 2*DM_) + wc*64 + ni*16 + lg*4 + r;  // h*64+z
                const int hh = nabs >> 6, z = nabs & 63;
                const float bias = bv[nabs];
#pragma unroll
                for (int mi = 0; mi < 4; mi++) {
                    const int mB = m0 + wr*64 + mi*16;
                    const int bb2 = mB >> 12, s0 = mB & (S_ - 1);
                    vtw[((long)(bb2*H_ + hh) * D_ + z) * S_ + s0 + lr] = f2bf(acc[mi][ni][r] + bias);
                }
            }
    }
}

// ---------------- Kernel 2: causal flash attention ----------------
// grid 768 XCD-swizzled, 128-thread blocks (2 waves), QBLK=64 with
// 32 q-rows/wave (2 slices): K/V LDS fragments read ONCE, reused for both
// slices -> ~2x less LDS-pipe traffic per element. Double-buffered
// gload_lds staging, swapped QK^T, shift-free exp2 softmax, ones-MFMA sum.
__global__ __launch_bounds__(128) void attn_kernel(
    const short* __restrict__ qws, const short* __restrict__ kws,
    const short* __restrict__ vtw, short* __restrict__ zws)
{
    __shared__ __align__(16) short KsL[2][4096];   // [64 kv][64 z] swizzled
    __shared__ __align__(16) short VsL[2][4096];   // [64 z][64 kv] swizzled
    __shared__ __align__(16) short PsL[2][32][72]; // [wave][q][kv]

    const int lin0 = blockIdx.x;
    const int lin  = (lin0 & 7) * 96 + (lin0 >> 3);     // 768 = 8*96, bijective
    const int pairidx = lin & 31;
    const int bh = lin >> 5;
    const int h = bh % H_, b = bh / H_;

    const int t = threadIdx.x, w = t >> 6, l = t & 63, lr = l & 15, lg = (l >> 4) & 3;
    const int lrow = l >> 3, lseg = l & 7;
    const long base = (long)(b*H_ + h) * S_ * D_;
    const int colo = (lseg ^ lrow) * 8;
    const int sw = (lr & 7) << 3;
    const int kb0 = lr*64 + ((lg*8) ^ sw);          // K/V LDS read bases (shorts)
    const int kb1 = lr*64 + ((32 + lg*8) ^ sw);

    bf8 ones;
#pragma unroll
    for (int i = 0; i < 8; i++) ones[i] = (short)0x3F80;   // 1.0 bf16

    for (int pass = 0; pass < 2; pass++) {
        const int qt = pass ? (63 - pairidx) : pairidx;
        const int nkv = qt + 1;

        bf8 qf[2][2];
#pragma unroll
        for (int sl = 0; sl < 2; sl++) {
            const short* src = qws + base + (long)(qt*64 + w*32 + sl*16 + lr) * D_ + lg*8;
            qf[sl][0] = *(const bf8*)src;
            qf[sl][1] = *(const bf8*)(src + 32);
        }
        f4 acc[2][4], accS[2];
#pragma unroll
        for (int sl = 0; sl < 2; sl++) {
#pragma unroll
            for (int nt = 0; nt < 4; nt++) acc[sl][nt] = (f4){0.f,0.f,0.f,0.f};
            accS[sl] = (f4){0.f,0.f,0.f,0.f};
        }

        const short* kcur = kws + base + (long)(w*32 + lrow) * D_ + colo;
        const short* vcur = vtw + base + (long)(w*32 + lrow) * S_ + colo;
        auto stage = [&](int bufi) {
#pragma unroll
            for (int qq = 0; qq < 4; qq++) {
                gll16(kcur + (long)qq*8*D_, &KsL[bufi][(w*32 + qq*8) * 64]);
                gll16(vcur + (long)qq*8*S_, &VsL[bufi][(w*32 + qq*8) * 64]);
            }
            kcur += 64*D_; vcur += 64;
        };

        stage(0);
        __syncthreads();

        for (int kvt = 0; kvt < nkv; kvt++) {
            const int cur = kvt & 1;
            if (kvt + 1 < nkv) stage(cur ^ 1);
            const short* Kc = KsL[cur];
            const short* Vc = VsL[cur];

            // S^T = K Q^T: lane holds P[q][kv = nt*16+lg*4+r], log2 domain.
            // K fragments read once, used by both q-slices.
            f4 sc[2][4];
            __builtin_amdgcn_s_setprio(1);
#pragma unroll
            for (int nt = 0; nt < 4; nt++) {
                bf8 k0 = *(const bf8*)(Kc + nt*1024 + kb0);
                bf8 k1 = *(const bf8*)(Kc + nt*1024 + kb1);
#pragma unroll
                for (int sl = 0; sl < 2; sl++) {
                    f4 z4 = (f4){0.f,0.f,0.f,0.f};
                    z4 = __builtin_amdgcn_mfma_f32_16x16x32_bf16(k0, qf[sl][0], z4, 0, 0, 0);
                    z4 = __builtin_amdgcn_mfma_f32_16x16x32_bf16(k1, qf[sl][1], z4, 0, 0, 0);
                    sc[sl][nt] = z4;
                }
            }
            __builtin_amdgcn_s_setprio(0);

            if (kvt == qt) {   // causal mask, diagonal tile only
#pragma unroll
                for (int sl = 0; sl < 2; sl++) {
                    const int qg = qt*64 + w*32 + sl*16 + lr;
#pragma unroll
                    for (int nt = 0; nt < 4; nt++)
#pragma unroll
                        for (int r = 0; r < 4; r++)
                            sc[sl][nt][r] = (kvt*64 + nt*16 + lg*4 + r <= qg) ? sc[sl][nt][r] : -1e30f;
                }
            }

            // shift-free exp2 + packed P -> LDS (b64 writes)
#pragma unroll
            for (int sl = 0; sl < 2; sl++) {
                short* prow = &PsL[w][sl*16 + lr][0];
#pragma unroll
                for (int nt = 0; nt < 4; nt++) {
                    const float p0 = exp2f(sc[sl][nt][0]);
                    const float p1 = exp2f(sc[sl][nt][1]);
                    const float p2 = exp2f(sc[sl][nt][2]);
                    const float p3 = exp2f(sc[sl][nt][3]);
                    const u32 lo = cvtpk(p0, p1), hi = cvtpk(p2, p3);
                    *(u64*)&prow[nt*16 + lg*4] = (u64)lo | ((u64)hi << 32);
                }
            }
            // PV (+ ones-column row-sum). V fragments read once, reused.
            bf8 pf[2][2];
#pragma unroll
            for (int sl = 0; sl < 2; sl++) {
                pf[sl][0] = *(const bf8*)&PsL[w][sl*16 + lr][lg*8];
                pf[sl][1] = *(const bf8*)&PsL[w][sl*16 + lr][32 + lg*8];
            }
            __builtin_amdgcn_s_setprio(1);
#pragma unroll
            for (int ntz = 0; ntz < 4; ntz++) {
                bf8 v0 = *(const bf8*)(Vc + ntz*1024 + kb0);
                bf8 v1 = *(const bf8*)(Vc + ntz*1024 + kb1);
#pragma unroll
                for (int sl = 0; sl < 2; sl++) {
                    acc[sl][ntz] = __builtin_amdgcn_mfma_f32_16x16x32_bf16(pf[sl][0], v0, acc[sl][ntz], 0, 0, 0);
                    acc[sl][ntz] = __builtin_amdgcn_mfma_f32_16x16x32_bf16(pf[sl][1], v1, acc[sl][ntz], 0, 0, 0);
                }
            }
#pragma unroll
            for (int sl = 0; sl < 2; sl++) {
                accS[sl] = __builtin_amdgcn_mfma_f32_16x16x32_bf16(pf[sl][0], ones, accS[sl], 0, 0, 0);
                accS[sl] = __builtin_amdgcn_mfma_f32_16x16x32_bf16(pf[sl][1], ones, accS[sl], 0, 0, 0);
            }
            __builtin_amdgcn_s_setprio(0);
            __syncthreads();   // drains vmcnt: next-tile stage done; all reads done
        }
        // epilogue: z[b][s][h*64+z] (contiguous per token for oproj)
#pragma unroll
        for (int sl = 0; sl < 2; sl++)
#pragma unroll
            for (int r = 0; r < 4; r++) {
                const float inv = 1.0f / accS[sl][r];
                const int srow = qt*64 + w*32 + sl*16 + lg*4 + r;
#pragma unroll
                for (int ntz = 0; ntz < 4; ntz++)
                    zws[((long)(b*S_ + srow)) * DM_ + h*D_ + ntz*16 + lr] = f2bf(acc[sl][ntz][r] * inv);
            }
    }
}

// ---------------- Kernel 3: output projection ----------------
// out[8192x768] = z[8192x768] * wo_t[768x768]^T + bo. 128x64 tile, BK=64.
__global__ __launch_bounds__(256) void oproj_kernel(
    const short* __restrict__ zws, const short* __restrict__ wo_t,
    const float* __restrict__ bo, float* __restrict__ out)
{
    __shared__ __align__(16) short As[2][8192];   // [128][64]
    __shared__ __align__(16) short Bs[2][4096];   // [64][64]

    const int o = (blockIdx.x & 7) * 96 + (blockIdx.x >> 3);
    const int by = o % 12, bx = o / 12;
    const int m0 = bx * 128, n0 = by * 64;
    const int t = threadIdx.x, w = t >> 6, l = t & 63, lr = l & 15, lg = (l >> 4) & 3;
    const int wr = w >> 1, wc = w & 1;
    const int lrow = l >> 3, lseg = l & 7;
    const int colo = (lseg ^ lrow) * 8;
    const int sw = (lr & 7) << 3;
    const int ab[2] = { (wr*64 + lr)*64 + ((lg*8) ^ sw), (wr*64 + lr)*64 + ((32 + lg*8) ^ sw) };
    const int bb[2] = { (wc*32 + lr)*64 + ((lg*8) ^ sw), (wc*32 + lr)*64 + ((32 + lg*8) ^ sw) };

    const short* zp = zws  + (long)(m0 + w*32 + lrow) * DM_ + colo;
    const short* wp = wo_t + (long)(n0 + w*16 + lrow) * DM_ + colo;

    auto stage = [&](int bufi) {
#pragma unroll
        for (int qq = 0; qq < 4; qq++)
            gll16(zp + qq*8*DM_, &As[bufi][(w*256 + qq*64) * 8]);
#pragma unroll
        for (int qq = 0; qq < 2; qq++)
            gll16(wp + qq*8*DM_, &Bs[bufi][(w*128 + qq*64) * 8]);
        zp += 64; wp += 64;
    };

    f4 acc[4][2];
#pragma unroll
    for (int mi = 0; mi < 4; mi++)
#pragma unroll
        for (int ni = 0; ni < 2; ni++) acc[mi][ni] = (f4){0.f,0.f,0.f,0.f};

    stage(0);
    __syncthreads();

    for (int k0 = 0, it = 0; k0 < DM_; k0 += 64, it++) {
        const int cur = it & 1;
        if (k0 + 64 < DM_) stage(cur ^ 1);
        const short* Ac = As[cur];
        const short* Bc = Bs[cur];
#pragma unroll
        for (int kh = 0; kh < 2; kh++) {
            bf8 af[4], bfr[2];
#pragma unroll
            for (int mi = 0; mi < 4; mi++) af[mi]  = *(const bf8*)(Ac + mi*1024 + ab[kh]);
#pragma unroll
            for (int ni = 0; ni < 2; ni++) bfr[ni] = *(const bf8*)(Bc + ni*1024 + bb[kh]);
#pragma unroll
            for (int mi = 0; mi < 4; mi++)
#pragma unroll
                for (int ni = 0; ni < 2; ni++)
                    acc[mi][ni] = __builtin_amdgcn_mfma_f32_16x16x32_bf16(af[mi], bfr[ni], acc[mi][ni], 0, 0, 0);
        }
        __syncthreads();
    }
#pragma unroll
    for (int ni = 0; ni < 2; ni++) {
        const int d = n0 + wc*32 + ni*16 + lr;
        const float bias = bo[d];
#pragma unroll
        for (int mi = 0; mi < 4; mi++)
#pragma unroll
            for (int r = 0; r < 4; r++) {
                const int m = m0 + wr*64 + mi*16 + lg*4 + r;
                out[(long)m * DM_ + d] = acc[mi][ni][r] + bias;
            }
    }
}

extern "C" void kernel_launch(void* const* d_in, const int* in_sizes, int n_in,
                              void* d_out, int out_size, void* d_ws, size_t ws_size,
                              hipStream_t stream)
{
    const float* x  = (const float*)d_in[0];
    const float* Wq = (const float*)d_in[1];
    const float* Wk = (const float*)d_in[2];
    const float* Wv = (const float*)d_in[3];
    const float* Wo = (const float*)d_in[4];
    const float* bq = (const float*)d_in[5];
    const float* bk = (const float*)d_in[6];
    const float* bv = (const float*)d_in[7];
    const float* bo = (const float*)d_in[8];
    float* out = (float*)d_out;

    // ws: xb (aliases zws: disjoint liveness) + q,k,vT + wcat + wo_t = 55.05 MB
    short* xb   = (short*)d_ws;
    short* zws  = xb;
    short* qws  = xb + NE;
    short* kws  = qws + NE;
    short* vtw  = kws + NE;
    short* wcat = vtw + NE;                // [2304][768] bf16 (e-major)
    short* wo_t = wcat + WQKV_ELEMS;       // [768][768]

    prep_kernel<<<3648, 256, 0, stream>>>(x, xb, Wq, Wk, Wv, Wo, wcat, wo_t);
    qkv_gemm<<<1152, 256, 0, stream>>>(xb, wcat, bq, bk, bv, qws, kws, vtw);
    attn_kernel<<<768, 128, 0, stream>>>(qws, kws, vtw, zws);
    oproj_kernel<<<768, 256, 0, stream>>>(zws, wo_t, bo, out);
}